// Round 2
// baseline (5125.794 us; speedup 1.0000x reference)
//
#include <hip/hip_runtime.h>

// HMGRUV2: 2-layer masked GRU scan. B=256, T=256, L=2, IN=256, H=256.
// All tensors are FLOAT32 (reference dtype; round-1 NaN falsified bf16).
// Persistent kernel, 1 workgroup per batch element; thread j owns hidden
// unit j (gate rows j, 256+j, 512+j). Masking algebra => at most 1 h-GEMV
// + 1 x-GEMV per layer per step, all branches wave-uniform.
// Weights transposed into d_ws as [k4][gate][j][float4] for coalesced
// 16B/lane loads (guarded by ws_size; direct-layout fallback otherwise).

#define BB 256
#define TT 256
#define HH 256
#define ININ 256
#define MAT_ELEMS 196608  // 256 * 768 per matrix view

__device__ __forceinline__ float sigm(float x) {
    return 1.0f / (1.0f + __expf(-x));
}
// tanh via exp, saturates correctly at +/-inf
__device__ __forceinline__ float tanhx(float x) {
    return 1.0f - 2.0f / (__expf(2.0f * x) + 1.0f);
}

// Transpose+regroup weights into ws (f32).
// Dest flat = m*196608 + k4*3072 + g*1024 + j*4 + e  (k = k4*4+e).
// Source: W_ih* is (768, 512) row-major [c][k], c = g*256+j (x-part k<256,
// h-part k>=256). W_hh* is (768, 256).
__global__ void transpose_weights(const float* __restrict__ W_ih0,
                                  const float* __restrict__ W_hh0,
                                  const float* __restrict__ W_ih1,
                                  const float* __restrict__ W_hh1,
                                  float* __restrict__ ws) {
    int tid = blockIdx.x * 256 + threadIdx.x;
    if (tid >= 6 * MAT_ELEMS) return;
    int m  = tid / MAT_ELEMS;
    int r  = tid % MAT_ELEMS;
    int k4 = r / 3072;
    int r2 = r % 3072;
    int g  = r2 / 1024;
    int r3 = r2 % 1024;
    int j  = r3 >> 2;
    int e  = r3 & 3;
    int k  = k4 * 4 + e;
    int c  = g * 256 + j;
    float v;
    switch (m) {
        case 0: v = W_ih0[c * 512 + k];        break;  // Wt_ih0x
        case 1: v = W_ih0[c * 512 + 256 + k];  break;  // Wt_ih0h
        case 2: v = W_hh0[c * 256 + k];        break;  // Wt_hh0
        case 3: v = W_ih1[c * 512 + k];        break;  // Wt_ih1x
        case 4: v = W_ih1[c * 512 + 256 + k];  break;  // Wt_ih1h
        default: v = W_hh1[c * 256 + k];       break;  // Wt_hh1
    }
    ws[tid] = v;
}

// One K=256 GEMV for hidden unit j's three gates, s in LDS (broadcast reads).
// TRANS: W is the transposed ws block, float4 idx (k4*3+g)*256+j.
// !TRANS: W is original row-major, row (g*256+j), row stride `stride` floats.
template <bool TRANS>
__device__ __forceinline__ void gemv3(const float* __restrict__ W, int stride,
                                      int j, const float* __restrict__ s,
                                      float& ar, float& az, float& an) {
    const float4* __restrict__ s4 = (const float4*)s;
    if (TRANS) {
        const float4* __restrict__ W4 = (const float4*)W;
#pragma unroll 4
        for (int k4 = 0; k4 < 64; ++k4) {
            float4 sv = s4[k4];
            float4 wr = W4[(k4 * 3 + 0) * 256 + j];
            float4 wz = W4[(k4 * 3 + 1) * 256 + j];
            float4 wn = W4[(k4 * 3 + 2) * 256 + j];
            ar += sv.x * wr.x + sv.y * wr.y + sv.z * wr.z + sv.w * wr.w;
            az += sv.x * wz.x + sv.y * wz.y + sv.z * wz.z + sv.w * wz.w;
            an += sv.x * wn.x + sv.y * wn.y + sv.z * wn.z + sv.w * wn.w;
        }
    } else {
        const float4* __restrict__ r0 = (const float4*)(W + (size_t)(0 * 256 + j) * stride);
        const float4* __restrict__ r1 = (const float4*)(W + (size_t)(1 * 256 + j) * stride);
        const float4* __restrict__ r2 = (const float4*)(W + (size_t)(2 * 256 + j) * stride);
#pragma unroll 4
        for (int k4 = 0; k4 < 64; ++k4) {
            float4 sv = s4[k4];
            float4 wr = r0[k4];
            float4 wz = r1[k4];
            float4 wn = r2[k4];
            ar += sv.x * wr.x + sv.y * wr.y + sv.z * wr.z + sv.w * wr.w;
            az += sv.x * wz.x + sv.y * wz.y + sv.z * wz.z + sv.w * wz.w;
            an += sv.x * wn.x + sv.y * wn.y + sv.z * wn.z + sv.w * wn.w;
        }
    }
}

template <bool TRANS>
__global__ __launch_bounds__(256) void hmgru_persistent(
    const float* __restrict__ x0, const float* __restrict__ x1,
    const float* __restrict__ hx0, const float* __restrict__ hx1,
    const float* __restrict__ b_ih0, const float* __restrict__ b_hh0,
    const float* __restrict__ b_ih1, const float* __restrict__ b_hh1,
    const int* __restrict__ dx, const int* __restrict__ dxlz,
    const float* __restrict__ W_ih0, const float* __restrict__ W_hh0,
    const float* __restrict__ W_ih1, const float* __restrict__ W_hh1,
    const float* __restrict__ Wt, float* __restrict__ out) {
    const int b = blockIdx.x;
    const int j = threadIdx.x;

    __shared__ float h0s[HH], h1s[HH], x0s[ININ], x1s[ININ];

    // Weight views: TRANS -> blocks of ws; !TRANS -> original matrices.
    const float* Wv_ih0x = TRANS ? Wt + 0 * MAT_ELEMS : W_ih0;        // stride 512
    const float* Wv_ih0h = TRANS ? Wt + 1 * MAT_ELEMS : W_ih0 + 256;  // stride 512
    const float* Wv_hh0  = TRANS ? Wt + 2 * MAT_ELEMS : W_hh0;        // stride 256
    const float* Wv_ih1x = TRANS ? Wt + 3 * MAT_ELEMS : W_ih1;        // stride 512
    const float* Wv_ih1h = TRANS ? Wt + 4 * MAT_ELEMS : W_ih1 + 256;  // stride 512
    const float* Wv_hh1  = TRANS ? Wt + 5 * MAT_ELEMS : W_hh1;        // stride 256

    // Per-thread biases (gate order r,z,n)
    const float bi0r = b_ih0[j], bi0z = b_ih0[256 + j], bi0n = b_ih0[512 + j];
    const float bh0r = b_hh0[j], bh0z = b_hh0[256 + j], bh0n = b_hh0[512 + j];
    const float bi1r = b_ih1[j], bi1z = b_ih1[256 + j], bi1n = b_ih1[512 + j];
    const float bh1r = b_hh1[j], bh1z = b_hh1[256 + j], bh1n = b_hh1[512 + j];

    // Constant h1n for (b1=0, dd1=1): xin1 = 0 and h1 = 0 -> bias-only GRU.
    const float c1r = sigm(bi1r + bh1r);
    const float c1z = sigm(bi1z + bh1z);
    const float c1n = tanhx(bi1n + c1r * bh1n);
    const float c1v = (1.0f - c1z) * c1n;

    float h0reg = hx0[b * HH + j];
    float h1reg = hx1[b * HH + j];
    h0s[j] = h0reg;
    h1s[j] = h1reg;

    const int* dxb  = dx + b * 2 * TT;   // dx[b][l][t]
    const int* dlzb = dxlz + b * TT;
    const float* x0b = x0 + (size_t)b * TT * ININ;
    const float* x1b = x1 + (size_t)b * TT * ININ;
    float* out0 = out + (size_t)b * TT * HH;          // out[0][b]
    float* out1 = out + (size_t)(BB + b) * TT * HH;   // out[1][b]

    for (int t = 0; t < TT; ++t) {
        x0s[j] = x0b[t * ININ + j];
        x1s[j] = x1b[t * ININ + j];
        const int b0  = dlzb[t];
        const int b1  = dxb[t];
        const int dd0 = t ? dxb[t - 1] : 0;
        const int dd1 = t ? dxb[TT + t - 1] : 0;
        __syncthreads();  // x ready; h stable from prev iter

        // ---------------- Layer 0 ----------------
        float h0n;
        if (b0 == 0 && dd0 == 0) {
            h0n = h0reg;  // pure carry
        } else {
            float ar = bi0r, az = bi0z, an = bi0n;
            if (b0)  gemv3<TRANS>(Wv_ih0x, 512, j, x0s, ar, az, an);
            if (dd0) gemv3<TRANS>(Wv_ih0h, 512, j, h1s, ar, az, an);
            float gr = bh0r, gz = bh0z, gn = bh0n;
            float h0cur = 0.0f;
            if (!dd0) {  // h0 = h0p survives; W_hh0 GEMV needed
                gemv3<TRANS>(Wv_hh0, 256, j, h0s, gr, gz, gn);
                h0cur = h0reg;
            }
            const float r = sigm(ar + gr);
            const float z = sigm(az + gz);
            const float n = tanhx(an + r * gn);
            h0n = (1.0f - z) * n + z * h0cur;
        }
        out0[t * HH + j] = h0n;
        __syncthreads();  // all reads of h0s done
        h0s[j] = h0n;
        h0reg  = h0n;
        __syncthreads();  // new h0s visible

        // ---------------- Layer 1 ----------------
        float h1n;
        if (b1 == 0) {
            h1n = dd1 ? c1v : h1reg;  // const-vector or pure carry
        } else {
            float ar = bi1r, az = bi1z, an = bi1n;
            gemv3<TRANS>(Wv_ih1x, 512, j, x1s, ar, az, an);
            gemv3<TRANS>(Wv_ih1h, 512, j, h0s, ar, az, an);  // uses NEW h0
            float gr = bh1r, gz = bh1z, gn = bh1n;
            float h1cur = 0.0f;
            if (!dd1) {
                gemv3<TRANS>(Wv_hh1, 256, j, h1s, gr, gz, gn);
                h1cur = h1reg;
            }
            const float r = sigm(ar + gr);
            const float z = sigm(az + gz);
            const float n = tanhx(an + r * gn);
            h1n = (1.0f - z) * n + z * h1cur;
        }
        out1[t * HH + j] = h1n;
        __syncthreads();  // all reads of h1s done
        h1s[j] = h1n;
        h1reg  = h1n;
        __syncthreads();  // new h1s visible before next iter
    }
}

extern "C" void kernel_launch(void* const* d_in, const int* in_sizes, int n_in,
                              void* d_out, int out_size, void* d_ws, size_t ws_size,
                              hipStream_t stream) {
    const float* x0    = (const float*)d_in[0];
    const float* x1    = (const float*)d_in[1];
    const float* hx0   = (const float*)d_in[2];
    const float* hx1   = (const float*)d_in[3];
    const float* W_ih0 = (const float*)d_in[4];
    const float* W_hh0 = (const float*)d_in[5];
    const float* b_ih0 = (const float*)d_in[6];
    const float* b_hh0 = (const float*)d_in[7];
    const float* W_ih1 = (const float*)d_in[8];
    const float* W_hh1 = (const float*)d_in[9];
    const float* b_ih1 = (const float*)d_in[10];
    const float* b_hh1 = (const float*)d_in[11];
    const int* dx      = (const int*)d_in[12];
    const int* dxlz    = (const int*)d_in[13];
    float* out = (float*)d_out;
    float* ws  = (float*)d_ws;

    const size_t ws_needed = (size_t)6 * MAT_ELEMS * sizeof(float);  // 4.72 MB
    const bool use_trans = (ws_size >= ws_needed) && (d_ws != nullptr);

    if (use_trans) {
        const int total = 6 * MAT_ELEMS;
        transpose_weights<<<(total + 255) / 256, 256, 0, stream>>>(W_ih0, W_hh0, W_ih1, W_hh1, ws);
        hmgru_persistent<true><<<BB, 256, 0, stream>>>(
            x0, x1, hx0, hx1, b_ih0, b_hh0, b_ih1, b_hh1, dx, dxlz,
            W_ih0, W_hh0, W_ih1, W_hh1, ws, out);
    } else {
        hmgru_persistent<false><<<BB, 256, 0, stream>>>(
            x0, x1, hx0, hx1, b_ih0, b_hh0, b_ih1, b_hh1, dx, dxlz,
            W_ih0, W_hh0, W_ih1, W_hh1, ws, out);
    }
}

// Round 3
// 3533.432 us; speedup vs baseline: 1.4507x; 1.4507x over previous
//
#include <hip/hip_runtime.h>

// HMGRUV2: 2-layer masked GRU scan. B=256, T=256, L=2, IN=256, H=256.
// f32 in/out. Persistent kernel, 1 WG per batch element, thread j owns
// hidden unit j. Round 3: f16-packed weights in d_ws (halves L2 bytes;
// 1.18 MB set fits per-XCD L2), v_dot2_f32_f16 inner loop (f32 accum),
// 2 barriers/step (double-buffered h/x), x(t+1) prefetch, LDS mask cache.

#define BB 256
#define TT 256
#define HH 256
#define ININ 256
#define MAT_U32 98304   // 768*256/2 u32 words per packed matrix
#define MAT_U4  24576   // uint4 words per packed matrix

typedef _Float16 f16;
typedef _Float16 f16x2 __attribute__((ext_vector_type(2)));

#if defined(__has_builtin)
#  if __has_builtin(__builtin_amdgcn_fdot2)
#    define HAVE_FDOT2 1
#  endif
#endif

__device__ __forceinline__ float dot2(f16x2 a, f16x2 b, float c) {
#ifdef HAVE_FDOT2
    return __builtin_amdgcn_fdot2(a, b, c, false);
#else
    return c + (float)a.x * (float)b.x + (float)a.y * (float)b.y;
#endif
}

union U4 { uint4 u; f16x2 h[4]; };

__device__ __forceinline__ float sigm(float x) { return 1.0f / (1.0f + __expf(-x)); }
__device__ __forceinline__ float tanhx(float x) { return 1.0f - 2.0f / (__expf(2.0f * x) + 1.0f); }

// Pack f32 weights -> f16 pairs in ws.
// Per matrix m: u32 flat = k8*3072 + g*1024 + j*4 + q ; covers k = k8*8+q*2,+1.
// Sources: W_ih* (768,512) row-major, row c=g*256+j (x: k<256, h: k>=256);
// W_hh* (768,256).
__global__ void pack_weights(const float* __restrict__ W_ih0,
                             const float* __restrict__ W_hh0,
                             const float* __restrict__ W_ih1,
                             const float* __restrict__ W_hh1,
                             unsigned int* __restrict__ ws) {
    int tid = blockIdx.x * 256 + threadIdx.x;
    if (tid >= 6 * MAT_U32) return;
    int m  = tid / MAT_U32;
    int r  = tid % MAT_U32;
    int k8 = r / 3072;
    int r2 = r % 3072;
    int g  = r2 / 1024;
    int r3 = r2 % 1024;
    int jj = r3 >> 2;
    int q  = r3 & 3;
    int k  = k8 * 8 + q * 2;
    int c  = g * 256 + jj;
    float lo, hi;
    switch (m) {
        case 0: lo = W_ih0[c * 512 + k];       hi = W_ih0[c * 512 + k + 1];       break;
        case 1: lo = W_ih0[c * 512 + 256 + k]; hi = W_ih0[c * 512 + 257 + k];     break;
        case 2: lo = W_hh0[c * 256 + k];       hi = W_hh0[c * 256 + k + 1];       break;
        case 3: lo = W_ih1[c * 512 + k];       hi = W_ih1[c * 512 + k + 1];       break;
        case 4: lo = W_ih1[c * 512 + 256 + k]; hi = W_ih1[c * 512 + 257 + k];     break;
        default: lo = W_hh1[c * 256 + k];      hi = W_hh1[c * 256 + k + 1];       break;
    }
    union { f16x2 h; unsigned int u; } pk;
    pk.h.x = (f16)lo;
    pk.h.y = (f16)hi;
    ws[tid] = pk.u;
}

// K=256 GEMV, 3 gates for unit j. W: packed uint4 matrix; s4: LDS vector as
// 32 uint4 (broadcast reads). f32 accumulate via v_dot2_f32_f16.
__device__ __forceinline__ void gemv3h(const uint4* __restrict__ W, int j,
                                       const uint4* __restrict__ s4,
                                       float& ar, float& az, float& an) {
#pragma unroll 8
    for (int k8 = 0; k8 < 32; ++k8) {
        U4 sv, wr, wz, wn;
        sv.u = s4[k8];
        wr.u = W[(k8 * 3 + 0) * 256 + j];
        wz.u = W[(k8 * 3 + 1) * 256 + j];
        wn.u = W[(k8 * 3 + 2) * 256 + j];
#pragma unroll
        for (int q = 0; q < 4; ++q) {
            ar = dot2(wr.h[q], sv.h[q], ar);
            az = dot2(wz.h[q], sv.h[q], az);
            an = dot2(wn.h[q], sv.h[q], an);
        }
    }
}

__global__ __launch_bounds__(256, 1) void hmgru_f16(
    const float* __restrict__ x0, const float* __restrict__ x1,
    const float* __restrict__ hx0, const float* __restrict__ hx1,
    const float* __restrict__ b_ih0, const float* __restrict__ b_hh0,
    const float* __restrict__ b_ih1, const float* __restrict__ b_hh1,
    const int* __restrict__ dx, const int* __restrict__ dxlz,
    const uint4* __restrict__ Wt, float* __restrict__ out) {
    const int b = blockIdx.x;
    const int j = threadIdx.x;

    const uint4* W_ih0x = Wt + 0 * MAT_U4;
    const uint4* W_ih0h = Wt + 1 * MAT_U4;
    const uint4* W_hh0  = Wt + 2 * MAT_U4;
    const uint4* W_ih1x = Wt + 3 * MAT_U4;
    const uint4* W_ih1h = Wt + 4 * MAT_U4;
    const uint4* W_hh1  = Wt + 5 * MAT_U4;

    __shared__ __align__(16) f16 h0s[2][HH], h1s[2][HH], x0sh[2][ININ], x1sh[2][ININ];
    __shared__ int m0s[TT], mAs[TT], mBs[TT];

    const float bi0r = b_ih0[j], bi0z = b_ih0[256 + j], bi0n = b_ih0[512 + j];
    const float bh0r = b_hh0[j], bh0z = b_hh0[256 + j], bh0n = b_hh0[512 + j];
    const float bi1r = b_ih1[j], bi1z = b_ih1[256 + j], bi1n = b_ih1[512 + j];
    const float bh1r = b_hh1[j], bh1z = b_hh1[256 + j], bh1n = b_hh1[512 + j];

    // (b1=0, dd1=1): xin1 = 0, h1 = 0 -> bias-only GRU constant.
    const float c1r = sigm(bi1r + bh1r);
    const float c1z = sigm(bi1z + bh1z);
    const float c1n = tanhx(bi1n + c1r * bh1n);
    const float c1v = (1.0f - c1z) * c1n;

    float h0reg = hx0[b * HH + j];
    float h1reg = hx1[b * HH + j];

    const int* dxb  = dx + b * 2 * TT;
    const int* dlzb = dxlz + b * TT;
    const float* x0b = x0 + (size_t)b * TT * ININ;
    const float* x1b = x1 + (size_t)b * TT * ININ;
    float* out0 = out + (size_t)b * TT * HH;          // out[0][b]
    float* out1 = out + (size_t)(BB + b) * TT * HH;   // out[1][b]

    h0s[0][j] = (f16)h0reg;
    h1s[0][j] = (f16)h1reg;
    x0sh[0][j] = (f16)x0b[j];
    x1sh[0][j] = (f16)x1b[j];
    m0s[j] = dlzb[j];
    mAs[j] = dxb[j];
    mBs[j] = dxb[TT + j];
    __syncthreads();

    int p = 0;
    for (int t = 0; t < TT; ++t) {
        // Prefetch x(t+1) into the other buffer (no one reads it this step).
        if (t + 1 < TT) {
            x0sh[p ^ 1][j] = (f16)x0b[(t + 1) * ININ + j];
            x1sh[p ^ 1][j] = (f16)x1b[(t + 1) * ININ + j];
        }
        const int b0  = m0s[t];
        const int b1  = mAs[t];
        const int dd0 = t ? mAs[t - 1] : 0;
        const int dd1 = t ? mBs[t - 1] : 0;

        const uint4* h0v = (const uint4*)h0s[p];
        const uint4* h1v = (const uint4*)h1s[p];
        const uint4* x0v = (const uint4*)x0sh[p];
        const uint4* x1v = (const uint4*)x1sh[p];

        // ---------------- Layer 0 ----------------
        float h0n;
        if ((b0 | dd0) == 0) {
            h0n = h0reg;  // pure carry
        } else {
            float ar = bi0r, az = bi0z, an = bi0n;
            if (b0)  gemv3h(W_ih0x, j, x0v, ar, az, an);
            if (dd0) gemv3h(W_ih0h, j, h1v, ar, az, an);
            float gr = bh0r, gz = bh0z, gn = bh0n;
            float h0cur = 0.0f;
            if (!dd0) {
                gemv3h(W_hh0, j, h0v, gr, gz, gn);
                h0cur = h0reg;
            }
            const float r = sigm(ar + gr);
            const float z = sigm(az + gz);
            const float n = tanhx(an + r * gn);
            h0n = (1.0f - z) * n + z * h0cur;
        }
        out0[t * HH + j] = h0n;
        h0s[p ^ 1][j] = (f16)h0n;
        h0reg = h0n;
        __syncthreads();  // barrier A: new h0 visible; h1s[p] untouched

        // ---------------- Layer 1 ----------------
        const uint4* h0nv = (const uint4*)h0s[p ^ 1];
        float h1n;
        if (b1 == 0) {
            h1n = dd1 ? c1v : h1reg;
        } else {
            float ar = bi1r, az = bi1z, an = bi1n;
            gemv3h(W_ih1x, j, x1v, ar, az, an);
            gemv3h(W_ih1h, j, h0nv, ar, az, an);  // new h0
            float gr = bh1r, gz = bh1z, gn = bh1n;
            float h1cur = 0.0f;
            if (!dd1) {
                gemv3h(W_hh1, j, h1v, gr, gz, gn);
                h1cur = h1reg;
            }
            const float r = sigm(ar + gr);
            const float z = sigm(az + gz);
            const float n = tanhx(an + r * gn);
            h1n = (1.0f - z) * n + z * h1cur;
        }
        out1[t * HH + j] = h1n;
        h1s[p ^ 1][j] = (f16)h1n;
        h1reg = h1n;
        __syncthreads();  // barrier B: step complete
        p ^= 1;
    }
}

// -------- f32 direct-layout fallback (only if d_ws is unusable) --------
__device__ __forceinline__ void gemv3f(const float* __restrict__ W, int stride,
                                       int j, const float* __restrict__ s,
                                       float& ar, float& az, float& an) {
    const float4* __restrict__ r0 = (const float4*)(W + (size_t)(0 * 256 + j) * stride);
    const float4* __restrict__ r1 = (const float4*)(W + (size_t)(1 * 256 + j) * stride);
    const float4* __restrict__ r2 = (const float4*)(W + (size_t)(2 * 256 + j) * stride);
    const float4* __restrict__ s4 = (const float4*)s;
#pragma unroll 4
    for (int k4 = 0; k4 < 64; ++k4) {
        float4 sv = s4[k4], wr = r0[k4], wz = r1[k4], wn = r2[k4];
        ar += sv.x * wr.x + sv.y * wr.y + sv.z * wr.z + sv.w * wr.w;
        az += sv.x * wz.x + sv.y * wz.y + sv.z * wz.z + sv.w * wz.w;
        an += sv.x * wn.x + sv.y * wn.y + sv.z * wn.z + sv.w * wn.w;
    }
}

__global__ __launch_bounds__(256) void hmgru_f32_fallback(
    const float* __restrict__ x0, const float* __restrict__ x1,
    const float* __restrict__ hx0, const float* __restrict__ hx1,
    const float* __restrict__ b_ih0, const float* __restrict__ b_hh0,
    const float* __restrict__ b_ih1, const float* __restrict__ b_hh1,
    const int* __restrict__ dx, const int* __restrict__ dxlz,
    const float* __restrict__ W_ih0, const float* __restrict__ W_hh0,
    const float* __restrict__ W_ih1, const float* __restrict__ W_hh1,
    float* __restrict__ out) {
    const int b = blockIdx.x;
    const int j = threadIdx.x;
    __shared__ float h0f[HH], h1f[HH], x0f[ININ], x1f[ININ];

    const float bi0r = b_ih0[j], bi0z = b_ih0[256 + j], bi0n = b_ih0[512 + j];
    const float bh0r = b_hh0[j], bh0z = b_hh0[256 + j], bh0n = b_hh0[512 + j];
    const float bi1r = b_ih1[j], bi1z = b_ih1[256 + j], bi1n = b_ih1[512 + j];
    const float bh1r = b_hh1[j], bh1z = b_hh1[256 + j], bh1n = b_hh1[512 + j];
    const float c1r = sigm(bi1r + bh1r);
    const float c1z = sigm(bi1z + bh1z);
    const float c1n = tanhx(bi1n + c1r * bh1n);
    const float c1v = (1.0f - c1z) * c1n;

    float h0reg = hx0[b * HH + j];
    float h1reg = hx1[b * HH + j];
    h0f[j] = h0reg; h1f[j] = h1reg;

    const int* dxb  = dx + b * 2 * TT;
    const int* dlzb = dxlz + b * TT;
    const float* x0b = x0 + (size_t)b * TT * ININ;
    const float* x1b = x1 + (size_t)b * TT * ININ;
    float* out0 = out + (size_t)b * TT * HH;
    float* out1 = out + (size_t)(BB + b) * TT * HH;

    for (int t = 0; t < TT; ++t) {
        x0f[j] = x0b[t * ININ + j];
        x1f[j] = x1b[t * ININ + j];
        const int b0 = dlzb[t], b1 = dxb[t];
        const int dd0 = t ? dxb[t - 1] : 0;
        const int dd1 = t ? dxb[TT + t - 1] : 0;
        __syncthreads();

        float h0n;
        if ((b0 | dd0) == 0) h0n = h0reg;
        else {
            float ar = bi0r, az = bi0z, an = bi0n;
            if (b0)  gemv3f(W_ih0, 512, j, x0f, ar, az, an);
            if (dd0) gemv3f(W_ih0 + 256, 512, j, h1f, ar, az, an);
            float gr = bh0r, gz = bh0z, gn = bh0n, h0cur = 0.0f;
            if (!dd0) { gemv3f(W_hh0, 256, j, h0f, gr, gz, gn); h0cur = h0reg; }
            float r = sigm(ar + gr), z = sigm(az + gz), n = tanhx(an + r * gn);
            h0n = (1.0f - z) * n + z * h0cur;
        }
        out0[t * HH + j] = h0n;
        __syncthreads();
        h0f[j] = h0n; h0reg = h0n;
        __syncthreads();

        float h1n;
        if (b1 == 0) h1n = dd1 ? c1v : h1reg;
        else {
            float ar = bi1r, az = bi1z, an = bi1n;
            gemv3f(W_ih1, 512, j, x1f, ar, az, an);
            gemv3f(W_ih1 + 256, 512, j, h0f, ar, az, an);
            float gr = bh1r, gz = bh1z, gn = bh1n, h1cur = 0.0f;
            if (!dd1) { gemv3f(W_hh1, 256, j, h1f, gr, gz, gn); h1cur = h1reg; }
            float r = sigm(ar + gr), z = sigm(az + gz), n = tanhx(an + r * gn);
            h1n = (1.0f - z) * n + z * h1cur;
        }
        out1[t * HH + j] = h1n;
        __syncthreads();
        h1f[j] = h1n; h1reg = h1n;
        __syncthreads();
    }
}

extern "C" void kernel_launch(void* const* d_in, const int* in_sizes, int n_in,
                              void* d_out, int out_size, void* d_ws, size_t ws_size,
                              hipStream_t stream) {
    const float* x0    = (const float*)d_in[0];
    const float* x1    = (const float*)d_in[1];
    const float* hx0   = (const float*)d_in[2];
    const float* hx1   = (const float*)d_in[3];
    const float* W_ih0 = (const float*)d_in[4];
    const float* W_hh0 = (const float*)d_in[5];
    const float* b_ih0 = (const float*)d_in[6];
    const float* b_hh0 = (const float*)d_in[7];
    const float* W_ih1 = (const float*)d_in[8];
    const float* W_hh1 = (const float*)d_in[9];
    const float* b_ih1 = (const float*)d_in[10];
    const float* b_hh1 = (const float*)d_in[11];
    const int* dx      = (const int*)d_in[12];
    const int* dxlz    = (const int*)d_in[13];
    float* out = (float*)d_out;

    const size_t ws_needed = (size_t)6 * MAT_U32 * sizeof(unsigned int);  // 2.36 MB
    if (d_ws != nullptr && ws_size >= ws_needed) {
        unsigned int* ws = (unsigned int*)d_ws;
        const int total = 6 * MAT_U32;
        pack_weights<<<(total + 255) / 256, 256, 0, stream>>>(W_ih0, W_hh0, W_ih1, W_hh1, ws);
        hmgru_f16<<<BB, 256, 0, stream>>>(x0, x1, hx0, hx1,
                                          b_ih0, b_hh0, b_ih1, b_hh1,
                                          dx, dxlz, (const uint4*)ws, out);
    } else {
        hmgru_f32_fallback<<<BB, 256, 0, stream>>>(x0, x1, hx0, hx1,
                                                   b_ih0, b_hh0, b_ih1, b_hh1,
                                                   dx, dxlz,
                                                   W_ih0, W_hh0, W_ih1, W_hh1, out);
    }
}

// Round 4
// 1824.356 us; speedup vs baseline: 2.8096x; 1.9368x over previous
//
#include <hip/hip_runtime.h>

// HMGRUV2: 2-layer masked GRU scan. B=256, T=256, L=2, IN=256, H=256 (f32 io).
// Round 4:
//  (a) x-projections gi = W_ih*x precomputed for all (b,t) via f16 MFMA GEMM
//      into d_ws (gated on ws_size) -> scan E[GEMVs/step] 2.5 -> 1.5.
//  (b) scan restructured split-K x4: 1024 threads = (kslice 0..3, j 0..255),
//      4 waves/SIMD to hide L2 latency; LDS reduction; epilogue on tid<256.
// Weights stay f16-packed in d_ws ([k8][gate][j] uint4 layout, L2-resident).

#define BB 256
#define TT 256
#define HH 256
#define MAT_U32 98304   // u32 words per packed matrix (768*256/2)
#define MAT_U4  24576   // uint4 words per packed matrix
#define NBT 65536       // B*T
#define GI_STRIDE 768

typedef unsigned int u32;
typedef _Float16 f16;
typedef _Float16 f16x2 __attribute__((ext_vector_type(2)));
typedef _Float16 f16x4 __attribute__((ext_vector_type(4)));
typedef _Float16 f16x8 __attribute__((ext_vector_type(8)));
typedef float f32x4 __attribute__((ext_vector_type(4)));

#if defined(__has_builtin)
#  if __has_builtin(__builtin_amdgcn_fdot2)
#    define HAVE_FDOT2 1
#  endif
#endif

__device__ __forceinline__ float dot2(f16x2 a, f16x2 b, float c) {
#ifdef HAVE_FDOT2
    return __builtin_amdgcn_fdot2(a, b, c, false);
#else
    return c + (float)a.x * (float)b.x + (float)a.y * (float)b.y;
#endif
}

union U4 { uint4 u; f16x2 h[4]; f16x8 v; };

__device__ __forceinline__ float sigm(float x) { return 1.0f / (1.0f + __expf(-x)); }
__device__ __forceinline__ float tanhx(float x) { return 1.0f - 2.0f / (__expf(2.0f * x) + 1.0f); }

// ---- pack f32 weights -> f16 pairs (round-3 proven layout) ----
// u32 flat (per matrix m) = k8*3072 + g*1024 + j*4 + q ; k = k8*8 + q*2 (+1).
__global__ void pack_weights(const float* __restrict__ W_ih0,
                             const float* __restrict__ W_hh0,
                             const float* __restrict__ W_ih1,
                             const float* __restrict__ W_hh1,
                             u32* __restrict__ ws) {
    int tid = blockIdx.x * 256 + threadIdx.x;
    if (tid >= 6 * MAT_U32) return;
    int m  = tid / MAT_U32;
    int r  = tid % MAT_U32;
    int k8 = r / 3072;
    int r2 = r % 3072;
    int g  = r2 / 1024;
    int r3 = r2 % 1024;
    int jj = r3 >> 2;
    int q  = r3 & 3;
    int k  = k8 * 8 + q * 2;
    int c  = g * 256 + jj;
    float lo, hi;
    switch (m) {
        case 0: lo = W_ih0[c * 512 + k];       hi = W_ih0[c * 512 + k + 1];   break;
        case 1: lo = W_ih0[c * 512 + 256 + k]; hi = W_ih0[c * 512 + 257 + k]; break;
        case 2: lo = W_hh0[c * 256 + k];       hi = W_hh0[c * 256 + k + 1];   break;
        case 3: lo = W_ih1[c * 512 + k];       hi = W_ih1[c * 512 + k + 1];   break;
        case 4: lo = W_ih1[c * 512 + 256 + k]; hi = W_ih1[c * 512 + 257 + k]; break;
        default: lo = W_hh1[c * 256 + k];      hi = W_hh1[c * 256 + k + 1];   break;
    }
    union { f16x2 h; u32 u; } pk;
    pk.h.x = (f16)lo;
    pk.h.y = (f16)hi;
    ws[tid] = pk.u;
}

// ---- MFMA GEMM: gi[layer][bt][m] = sum_k W_ihLx[m][k] * x[bt][k]  (f16) ----
// Fragment layouts (measured, m89/m91/m120): A[m=lane&15][k=quad*8+i],
// B holds X[n=lane&15][k=quad*8+i]; D: col(n)=lane&15, row(m)=quad*4+reg.
__global__ __launch_bounds__(256, 2) void proj_gemm(
    const float* __restrict__ x0, const float* __restrict__ x1,
    const uint4* __restrict__ Wt, f16* __restrict__ gi) {
    const int nblk  = blockIdx.x & 1023;
    const int layer = blockIdx.x >> 10;
    const int bt0   = nblk * 64;
    const float4* __restrict__ X4 = (const float4*)(layer ? x1 : x0);
    const uint4*  __restrict__ W  = Wt + (layer ? 3 : 0) * MAT_U4;
    f16* __restrict__ giL = gi + (size_t)layer * NBT * GI_STRIDE;

    __shared__ __align__(16) f16 xs[64 * 264];  // 64 rows x 256 f16, +8 pad

    const int tid = threadIdx.x;
    // stage 64x256 f32 -> f16 LDS
    for (int it = 0; it < 16; ++it) {
        int idx = it * 256 + tid;
        int r = idx >> 6, c4 = idx & 63;
        float4 v = X4[(size_t)(bt0 + r) * 64 + c4];
        union { f16x4 h; unsigned long long u; } pk;
        pk.h = (f16x4){(f16)v.x, (f16)v.y, (f16)v.z, (f16)v.w};
        *(unsigned long long*)((char*)xs + r * 528 + c4 * 8) = pk.u;
    }
    __syncthreads();

    const int wave = tid >> 6;
    const int lane = tid & 63;
    const int l16  = lane & 15;
    const int quad = lane >> 4;

    for (int i = 0; i < 12; ++i) {
        const int mt = i * 4 + wave;   // m-tile 0..47
        const int m0 = mt * 16;
        const int g  = m0 >> 8;
        const int j0 = m0 & 255;
        f16x8 afr[8];
#pragma unroll
        for (int kst = 0; kst < 8; ++kst) {
            U4 a;
            a.u = W[((kst * 4 + quad) * 3 + g) * 256 + (j0 + l16)];
            afr[kst] = a.v;
        }
#pragma unroll
        for (int nt = 0; nt < 4; ++nt) {
            const int n0 = nt * 16;
            f32x4 acc = {0.f, 0.f, 0.f, 0.f};
#pragma unroll
            for (int kst = 0; kst < 8; ++kst) {
                f16x8 bfr = *(const f16x8*)((const char*)xs +
                               (n0 + l16) * 528 + kst * 64 + quad * 16);
                acc = __builtin_amdgcn_mfma_f32_16x16x32_f16(afr[kst], bfr, acc, 0, 0, 0);
            }
            const int col = bt0 + n0 + l16;
            union { f16x4 h; unsigned long long u; } o;
            o.h = (f16x4){(f16)acc[0], (f16)acc[1], (f16)acc[2], (f16)acc[3]};
            *(unsigned long long*)(giL + (size_t)col * GI_STRIDE + m0 + quad * 4) = o.u;
        }
    }
}

// ---- split-K partial GEMV: 8 k8-groups (64 k) for unit j's three gates ----
__device__ __forceinline__ void gemv3p(const uint4* __restrict__ W, int j, int ksb,
                                       const uint4* __restrict__ s4,
                                       float& pr, float& pz, float& pn) {
#pragma unroll 4
    for (int i = 0; i < 8; ++i) {
        const int k8 = ksb + i;
        U4 sv, wr, wz, wn;
        sv.u = s4[k8];
        wr.u = W[(k8 * 3 + 0) * 256 + j];
        wz.u = W[(k8 * 3 + 1) * 256 + j];
        wn.u = W[(k8 * 3 + 2) * 256 + j];
#pragma unroll
        for (int q = 0; q < 4; ++q) {
            pr = dot2(wr.h[q], sv.h[q], pr);
            pz = dot2(wz.h[q], sv.h[q], pz);
            pn = dot2(wn.h[q], sv.h[q], pn);
        }
    }
}

template <bool PRECOMP>
__global__ __launch_bounds__(1024, 4) void hmgru_scan(
    const float* __restrict__ x0, const float* __restrict__ x1,
    const float* __restrict__ hx0, const float* __restrict__ hx1,
    const float* __restrict__ b_ih0, const float* __restrict__ b_hh0,
    const float* __restrict__ b_ih1, const float* __restrict__ b_hh1,
    const int* __restrict__ dx, const int* __restrict__ dxlz,
    const uint4* __restrict__ Wt, const f16* __restrict__ gi,
    float* __restrict__ out) {
    const int b   = blockIdx.x;
    const int tid = threadIdx.x;
    const int j   = tid & 255;
    const int ks  = tid >> 8;
    const int ksb = ks * 8;

    const uint4* W_ih0x = Wt + 0 * MAT_U4;
    const uint4* W_ih0h = Wt + 1 * MAT_U4;
    const uint4* W_hh0  = Wt + 2 * MAT_U4;
    const uint4* W_ih1x = Wt + 3 * MAT_U4;
    const uint4* W_ih1h = Wt + 4 * MAT_U4;
    const uint4* W_hh1  = Wt + 5 * MAT_U4;
    const f16* gi0 = gi;
    const f16* gi1 = gi + (size_t)NBT * GI_STRIDE;

    __shared__ __align__(16) f16 h0s[2][256], h1s[2][256];
    __shared__ __align__(16) f16 x0sh[2][256], x1sh[2][256];  // fallback only
    __shared__ float rbuf[6 * 4 * 256];                       // [c][ks][j]
    __shared__ int m0s[TT], mAs[TT], mBs[TT];

    const float bi0r = b_ih0[j], bi0z = b_ih0[256 + j], bi0n = b_ih0[512 + j];
    const float bh0r = b_hh0[j], bh0z = b_hh0[256 + j], bh0n = b_hh0[512 + j];
    const float bi1r = b_ih1[j], bi1z = b_ih1[256 + j], bi1n = b_ih1[512 + j];
    const float bh1r = b_hh1[j], bh1z = b_hh1[256 + j], bh1n = b_hh1[512 + j];

    // (b1=0, dd1=1): bias-only GRU constant.
    const float c1r = sigm(bi1r + bh1r);
    const float c1z = sigm(bi1z + bh1z);
    const float c1n = tanhx(bi1n + c1r * bh1n);
    const float c1v = (1.0f - c1z) * c1n;

    float h0reg = hx0[b * HH + j];
    float h1reg = hx1[b * HH + j];

    const int* dxb  = dx + b * 2 * TT;
    const int* dlzb = dxlz + b * TT;
    const float* x0b = x0 + (size_t)b * TT * 256;
    const float* x1b = x1 + (size_t)b * TT * 256;
    float* out0 = out + (size_t)b * TT * HH;
    float* out1 = out + (size_t)(BB + b) * TT * HH;

    if (tid < 256) {
        h0s[0][j] = (f16)h0reg;
        h1s[0][j] = (f16)h1reg;
        if (!PRECOMP) {
            x0sh[0][j] = (f16)x0b[j];
            x1sh[0][j] = (f16)x1b[j];
        }
        m0s[j] = dlzb[j];
        mAs[j] = dxb[j];
        mBs[j] = dxb[TT + j];
    }
    __syncthreads();

    int p = 0;
    for (int t = 0; t < TT; ++t) {
        const int b0  = m0s[t];
        const int b1  = mAs[t];
        const int dd0 = t ? mAs[t - 1] : 0;
        const int dd1 = t ? mBs[t - 1] : 0;
        const int bt  = b * TT + t;

        // fallback: prefetch x(t+1) into the other buffer
        if (!PRECOMP && tid < 256 && (t + 1) < TT) {
            x0sh[p ^ 1][j] = (f16)x0b[(t + 1) * 256 + j];
            x1sh[p ^ 1][j] = (f16)x1b[(t + 1) * 256 + j];
        }
        // precomp: prefetch gi rows into registers (hidden behind GEMVs)
        float g0r = 0.f, g0z = 0.f, g0n = 0.f, g1r = 0.f, g1z = 0.f, g1n = 0.f;
        if (PRECOMP && tid < 256) {
            if (b0) {
                const f16* pg = gi0 + (size_t)bt * GI_STRIDE;
                g0r = (float)pg[j]; g0z = (float)pg[256 + j]; g0n = (float)pg[512 + j];
            }
            if (b1) {
                const f16* pg = gi1 + (size_t)bt * GI_STRIDE;
                g1r = (float)pg[j]; g1z = (float)pg[256 + j]; g1n = (float)pg[512 + j];
            }
        }

        // ---------------- Layer 0 ----------------
        const bool l0g = (b0 | dd0) != 0;
        if (l0g) {
            float pir = 0.f, piz = 0.f, pin = 0.f, phr = 0.f, phz = 0.f, phn = 0.f;
            if (!PRECOMP && b0) gemv3p(W_ih0x, j, ksb, (const uint4*)x0sh[p], pir, piz, pin);
            if (dd0)            gemv3p(W_ih0h, j, ksb, (const uint4*)h1s[p], pir, piz, pin);
            if (!dd0)           gemv3p(W_hh0,  j, ksb, (const uint4*)h0s[p], phr, phz, phn);
            rbuf[(0 * 4 + ks) * 256 + j] = pir;
            rbuf[(1 * 4 + ks) * 256 + j] = piz;
            rbuf[(2 * 4 + ks) * 256 + j] = pin;
            rbuf[(3 * 4 + ks) * 256 + j] = phr;
            rbuf[(4 * 4 + ks) * 256 + j] = phz;
            rbuf[(5 * 4 + ks) * 256 + j] = phn;
            __syncthreads();  // B1: partials visible
        }
        if (tid < 256) {
            float h0n;
            if (!l0g) {
                h0n = h0reg;  // pure carry
            } else {
                float air = g0r, aiz = g0z, ain = g0n;
                float ahr = 0.f, ahz = 0.f, ahn = 0.f;
#pragma unroll
                for (int s = 0; s < 4; ++s) {
                    air += rbuf[(0 * 4 + s) * 256 + j];
                    aiz += rbuf[(1 * 4 + s) * 256 + j];
                    ain += rbuf[(2 * 4 + s) * 256 + j];
                    ahr += rbuf[(3 * 4 + s) * 256 + j];
                    ahz += rbuf[(4 * 4 + s) * 256 + j];
                    ahn += rbuf[(5 * 4 + s) * 256 + j];
                }
                const float ar = bi0r + air, az = bi0z + aiz, an = bi0n + ain;
                const float gr = bh0r + ahr, gz = bh0z + ahz, gn = bh0n + ahn;
                const float h0cur = dd0 ? 0.0f : h0reg;
                const float r = sigm(ar + gr);
                const float z = sigm(az + gz);
                const float n = tanhx(an + r * gn);
                h0n = (1.0f - z) * n + z * h0cur;
            }
            out0[t * HH + j] = h0n;
            h0s[p ^ 1][j] = (f16)h0n;
            h0reg = h0n;
        }
        __syncthreads();  // B2: new h0 visible, rbuf free

        // ---------------- Layer 1 ----------------
        if (b1) {
            float pir = 0.f, piz = 0.f, pin = 0.f, phr = 0.f, phz = 0.f, phn = 0.f;
            if (!PRECOMP) gemv3p(W_ih1x, j, ksb, (const uint4*)x1sh[p], pir, piz, pin);
            gemv3p(W_ih1h, j, ksb, (const uint4*)h0s[p ^ 1], pir, piz, pin);  // new h0
            if (!dd1) gemv3p(W_hh1, j, ksb, (const uint4*)h1s[p], phr, phz, phn);
            rbuf[(0 * 4 + ks) * 256 + j] = pir;
            rbuf[(1 * 4 + ks) * 256 + j] = piz;
            rbuf[(2 * 4 + ks) * 256 + j] = pin;
            rbuf[(3 * 4 + ks) * 256 + j] = phr;
            rbuf[(4 * 4 + ks) * 256 + j] = phz;
            rbuf[(5 * 4 + ks) * 256 + j] = phn;
            __syncthreads();  // B3
        }
        if (tid < 256) {
            float h1n;
            if (!b1) {
                h1n = dd1 ? c1v : h1reg;
            } else {
                float air = g1r, aiz = g1z, ain = g1n;
                float ahr = 0.f, ahz = 0.f, ahn = 0.f;
#pragma unroll
                for (int s = 0; s < 4; ++s) {
                    air += rbuf[(0 * 4 + s) * 256 + j];
                    aiz += rbuf[(1 * 4 + s) * 256 + j];
                    ain += rbuf[(2 * 4 + s) * 256 + j];
                    ahr += rbuf[(3 * 4 + s) * 256 + j];
                    ahz += rbuf[(4 * 4 + s) * 256 + j];
                    ahn += rbuf[(5 * 4 + s) * 256 + j];
                }
                const float ar = bi1r + air, az = bi1z + aiz, an = bi1n + ain;
                const float gr = bh1r + ahr, gz = bh1z + ahz, gn = bh1n + ahn;
                const float h1cur = dd1 ? 0.0f : h1reg;
                const float r = sigm(ar + gr);
                const float z = sigm(az + gz);
                const float n = tanhx(an + r * gn);
                h1n = (1.0f - z) * n + z * h1cur;
            }
            out1[t * HH + j] = h1n;
            h1s[p ^ 1][j] = (f16)h1n;
            h1reg = h1n;
        }
        __syncthreads();  // B4: new h1 visible, rbuf free
        p ^= 1;
    }
}

extern "C" void kernel_launch(void* const* d_in, const int* in_sizes, int n_in,
                              void* d_out, int out_size, void* d_ws, size_t ws_size,
                              hipStream_t stream) {
    const float* x0    = (const float*)d_in[0];
    const float* x1    = (const float*)d_in[1];
    const float* hx0   = (const float*)d_in[2];
    const float* hx1   = (const float*)d_in[3];
    const float* W_ih0 = (const float*)d_in[4];
    const float* W_hh0 = (const float*)d_in[5];
    const float* b_ih0 = (const float*)d_in[6];
    const float* b_hh0 = (const float*)d_in[7];
    const float* W_ih1 = (const float*)d_in[8];
    const float* W_hh1 = (const float*)d_in[9];
    const float* b_ih1 = (const float*)d_in[10];
    const float* b_hh1 = (const float*)d_in[11];
    const int* dx      = (const int*)d_in[12];
    const int* dxlz    = (const int*)d_in[13];
    float* out = (float*)d_out;

    const size_t sz_w  = (size_t)6 * MAT_U32 * sizeof(u32);        // 2.36 MB (proven to fit, round 3)
    const size_t sz_gi = (size_t)2 * NBT * GI_STRIDE * sizeof(f16); // 201.3 MB
    const bool precomp = (d_ws != nullptr) && (ws_size >= sz_w + sz_gi);

    u32* ws = (u32*)d_ws;
    const int total = 6 * MAT_U32;
    pack_weights<<<(total + 255) / 256, 256, 0, stream>>>(W_ih0, W_hh0, W_ih1, W_hh1, ws);

    f16* gi = (f16*)((char*)d_ws + sz_w);
    if (precomp) {
        proj_gemm<<<2048, 256, 0, stream>>>(x0, x1, (const uint4*)ws, gi);
        hmgru_scan<true><<<BB, 1024, 0, stream>>>(
            x0, x1, hx0, hx1, b_ih0, b_hh0, b_ih1, b_hh1, dx, dxlz,
            (const uint4*)ws, gi, out);
    } else {
        hmgru_scan<false><<<BB, 1024, 0, stream>>>(
            x0, x1, hx0, hx1, b_ih0, b_hh0, b_ih1, b_hh1, dx, dxlz,
            (const uint4*)ws, gi, out);
    }
}